// Round 5
// baseline (544.833 us; speedup 1.0000x reference)
//
#include <hip/hip_runtime.h>
#include <hip/hip_bf16.h>
#include <math.h>

// ---------------- setup kernels ----------------

__global__ void zero_kernel(float* p, int n) {
    int i = blockIdx.x * blockDim.x + threadIdx.x;
    if (i < n) p[i] = 0.f;
}

// single-atomic histogram: rank[i] = old count of dst
__global__ void rank_kernel(const int* __restrict__ ei, int* __restrict__ cnt,
                            int* __restrict__ rank, int E) {
    int i = blockIdx.x * blockDim.x + threadIdx.x;
    if (i >= E) return;
    int dst = __builtin_nontemporal_load(ei + E + i);
    rank[i] = atomicAdd(&cnt[dst], 1);
}

// --- 3-kernel exclusive scan of cnt -> row_ptr ---
__global__ void scan1(const int* cnt, int* row_ptr, int* blockSums, int n) {
    __shared__ int sh[1024];
    int i = blockIdx.x * 1024 + threadIdx.x;
    int v = (i < n) ? cnt[i] : 0;
    sh[threadIdx.x] = v;
    __syncthreads();
    for (int off = 1; off < 1024; off <<= 1) {
        int t = 0;
        if (threadIdx.x >= off) t = sh[threadIdx.x - off];
        __syncthreads();
        sh[threadIdx.x] += t;
        __syncthreads();
    }
    if (i < n) row_ptr[i] = sh[threadIdx.x] - v;
    if (threadIdx.x == 1023) blockSums[blockIdx.x] = sh[1023];
}

__global__ void scan2(int* blockSums, int nb) {
    if (threadIdx.x == 0 && blockIdx.x == 0) {
        int run = 0;
        for (int i = 0; i < nb; i++) { int v = blockSums[i]; blockSums[i] = run; run += v; }
    }
}

__global__ void scan3(int* row_ptr, const int* blockSums, int n, int E) {
    int i = blockIdx.x * 1024 + threadIdx.x;
    if (i < n) row_ptr[i] += blockSums[blockIdx.x];
    if (i == 0) row_ptr[n] = E;
}

// place edges: pos = row_ptr[dst] + rank[i]; single 8B scattered store (src, ew)
__global__ void place2(const int* __restrict__ ei, const float* __restrict__ ew,
                       const int* __restrict__ rank, const int* __restrict__ row_ptr,
                       int2* __restrict__ csr, int E) {
    int i = blockIdx.x * blockDim.x + threadIdx.x;
    if (i >= E) return;
    int s = __builtin_nontemporal_load(ei + i);
    int d = __builtin_nontemporal_load(ei + E + i);
    int pos = row_ptr[d] + rank[i];
    csr[pos] = make_int2(s, __float_as_int(ew[i]));
}

// weighted degree from CSR (no atomics) -> dis = 1/sqrt(deg)
__global__ void wdeg_dis(const int2* __restrict__ csr, const int* __restrict__ row_ptr,
                         float* __restrict__ dis, int n) {
    int node = blockIdx.x * blockDim.x + threadIdx.x;
    if (node >= n) return;
    int p = row_ptr[node], end = row_ptr[node + 1];
    float s = 0.f;
    for (; p < end; p++) s += __int_as_float(csr[p].y);
    dis[node] = (s > 0.f) ? (1.0f / sqrtf(s)) : 0.f;
}

// csr.y <- dis[dst]*dis[src]*ew   (in place)
__global__ void normk(int2* __restrict__ csr, const int* __restrict__ row_ptr,
                      const float* __restrict__ dis, int n) {
    int node = blockIdx.x * blockDim.x + threadIdx.x;
    if (node >= n) return;
    int p = row_ptr[node], end = row_ptr[node + 1];
    float dn = dis[node];
    for (; p < end; p++) {
        int2 e = csr[p];
        csr[p].y = __float_as_int(__int_as_float(e.y) * dn * dis[e.x]);
    }
}

// ---------------- conv1 (bf16 features, row stride 64 = 128B) ----------------

// rank-1 collapse of t=0: y[n] = sum_e norm_e * x[src_e]
__global__ void aggx(const float* __restrict__ x, const int* __restrict__ row_ptr,
                     const int2* __restrict__ csr, float* __restrict__ y, int n) {
    int node = blockIdx.x * blockDim.x + threadIdx.x;
    if (node >= n) return;
    const long long* csr8 = (const long long*)csr;
    int p = row_ptr[node], end = row_ptr[node + 1];
    float a0 = 0.f, a1 = 0.f, a2 = 0.f, a3 = 0.f, a4 = 0.f, a5 = 0.f, a6 = 0.f, a7 = 0.f;
    for (; p + 7 < end; p += 8) {
        long long e0 = __builtin_nontemporal_load(csr8 + p + 0);
        long long e1 = __builtin_nontemporal_load(csr8 + p + 1);
        long long e2 = __builtin_nontemporal_load(csr8 + p + 2);
        long long e3 = __builtin_nontemporal_load(csr8 + p + 3);
        long long e4 = __builtin_nontemporal_load(csr8 + p + 4);
        long long e5 = __builtin_nontemporal_load(csr8 + p + 5);
        long long e6 = __builtin_nontemporal_load(csr8 + p + 6);
        long long e7 = __builtin_nontemporal_load(csr8 + p + 7);
        a0 += x[(int)e0] * __int_as_float((int)(e0 >> 32));
        a1 += x[(int)e1] * __int_as_float((int)(e1 >> 32));
        a2 += x[(int)e2] * __int_as_float((int)(e2 >> 32));
        a3 += x[(int)e3] * __int_as_float((int)(e3 >> 32));
        a4 += x[(int)e4] * __int_as_float((int)(e4 >> 32));
        a5 += x[(int)e5] * __int_as_float((int)(e5 >> 32));
        a6 += x[(int)e6] * __int_as_float((int)(e6 >> 32));
        a7 += x[(int)e7] * __int_as_float((int)(e7 >> 32));
    }
    for (; p < end; p++) {
        long long e = __builtin_nontemporal_load(csr8 + p);
        a0 += x[(int)e] * __int_as_float((int)(e >> 32));
    }
    y[node] = ((a0 + a1) + (a2 + a3)) + ((a4 + a5) + (a6 + a7));
}

// out_0 = relu(y*w_init + x*w_root + b), bf16, pad channels 48..63 with 0
__global__ void init48(const float* __restrict__ x, const float* __restrict__ y,
                       const float* __restrict__ w_init, const float* __restrict__ w_root,
                       const float* __restrict__ w_b, __hip_bfloat16* __restrict__ P, int n) {
    unsigned t = blockIdx.x * blockDim.x + threadIdx.x;
    if (t >= (unsigned)n * 64u) return;
    unsigned node = t >> 6, c = t & 63;
    float v = 0.f;
    if (c < 48) v = fmaxf(y[node] * w_init[c] + x[node] * w_root[c] + w_b[c], 0.f);
    P[t] = __float2bfloat16(v);
}

// fused step t>=1: P_out = relu( (A*P_in)*W + x*w_root + b )
// wave per node, TWO edges per wave iteration: half h = lane>>5 owns edge slot,
// lane's dword j = lane&31 covers channels (2j, 2j+1). 32-bit saddr offsets.
__global__ void __launch_bounds__(256) agg48p(
    const __hip_bfloat16* __restrict__ P, const float* __restrict__ W,
    const float* __restrict__ x, const float* __restrict__ w_root,
    const float* __restrict__ w_b, const int* __restrict__ row_ptr,
    const int2* __restrict__ csr, __hip_bfloat16* __restrict__ Pout, int n) {
    int wid = (int)((blockIdx.x * blockDim.x + threadIdx.x) >> 6);
    int lane = threadIdx.x & 63;
    if (wid >= n) return;
    int h = lane >> 5;            // edge slot within pair
    unsigned loff = (unsigned)((lane & 31) << 2);  // byte offset of dword j in row
    const char* Pb = (const char*)P;
    const long long* csr8 = (const long long*)csr;

    int start = row_ptr[wid], end = row_ptr[wid + 1];
    int p = start;
    float l0 = 0.f, l1 = 0.f, l2 = 0.f, l3 = 0.f;
    float h0 = 0.f, h1 = 0.f, h2 = 0.f, h3 = 0.f;
    // main: 4 pairs = 8 edges per iteration
    for (; p + 8 <= end; p += 8) {
        long long e0 = __builtin_nontemporal_load(csr8 + p + 0 + h);
        long long e1 = __builtin_nontemporal_load(csr8 + p + 2 + h);
        long long e2 = __builtin_nontemporal_load(csr8 + p + 4 + h);
        long long e3 = __builtin_nontemporal_load(csr8 + p + 6 + h);
        unsigned o0 = (((unsigned)(int)e0) << 7) + loff;
        unsigned o1 = (((unsigned)(int)e1) << 7) + loff;
        unsigned o2 = (((unsigned)(int)e2) << 7) + loff;
        unsigned o3 = (((unsigned)(int)e3) << 7) + loff;
        unsigned u0 = *(const unsigned*)(Pb + o0);
        unsigned u1 = *(const unsigned*)(Pb + o1);
        unsigned u2 = *(const unsigned*)(Pb + o2);
        unsigned u3 = *(const unsigned*)(Pb + o3);
        float w0 = __int_as_float((int)(e0 >> 32));
        float w1 = __int_as_float((int)(e1 >> 32));
        float w2 = __int_as_float((int)(e2 >> 32));
        float w3 = __int_as_float((int)(e3 >> 32));
        l0 += __int_as_float(u0 << 16) * w0;
        h0 += __int_as_float(u0 & 0xffff0000u) * w0;
        l1 += __int_as_float(u1 << 16) * w1;
        h1 += __int_as_float(u1 & 0xffff0000u) * w1;
        l2 += __int_as_float(u2 << 16) * w2;
        h2 += __int_as_float(u2 & 0xffff0000u) * w2;
        l3 += __int_as_float(u3 << 16) * w3;
        h3 += __int_as_float(u3 & 0xffff0000u) * w3;
    }
    // tail: one predicated pair per iteration (<=4 iters)
    for (; p < end; p += 2) {
        int idx = p + h;
        bool valid = idx < end;
        long long e = __builtin_nontemporal_load(csr8 + (valid ? idx : p));
        float w = valid ? __int_as_float((int)(e >> 32)) : 0.f;
        unsigned o = (((unsigned)(int)e) << 7) + loff;
        unsigned u = *(const unsigned*)(Pb + o);
        l0 += __int_as_float(u << 16) * w;
        h0 += __int_as_float(u & 0xffff0000u) * w;
    }
    float Slo = (l0 + l1) + (l2 + l3);
    float Shi = (h0 + h1) + (h2 + h3);
    // combine the two half-wave edge streams
    Slo += __shfl_xor(Slo, 32);
    Shi += __shfl_xor(Shi, 32);
    // now every lane holds S for channels (2(lane&31), 2(lane&31)+1)

    // in-register 16x16 per-stack transform: lane computes output channel c = lane
    int c = lane;
    int k = c >> 4;
    int kk = (k < 3) ? k : 0;
    float wv[16];
#pragma unroll
    for (int i = 0; i < 16; i++) wv[i] = W[kk * 256 + i * 16 + (c & 15)];
    float rootc = 0.f;
    if (c < 48) rootc = x[wid] * w_root[c] + w_b[c];
    float acc = 0.f;
    int bl = kk << 3;  // source pair-lane base = k*8
#pragma unroll
    for (int i2 = 0; i2 < 8; i2++) {
        acc += __shfl(Slo, bl + i2) * wv[2 * i2];
        acc += __shfl(Shi, bl + i2) * wv[2 * i2 + 1];
    }
    float r = (c < 48) ? fmaxf(acc + rootc, 0.f) : 0.f;

    // pack two channels -> one bf16x2 dword; lanes 0..31 store the 128B row
    __hip_bfloat16 hb = __float2bfloat16(r);
    unsigned bu = (unsigned)*reinterpret_cast<unsigned short*>(&hb);
    int j2 = (lane & 31) << 1;
    unsigned lo = (unsigned)__shfl((int)bu, j2);
    unsigned hi = (unsigned)__shfl((int)bu, j2 + 1);
    if (lane < 32) {
        unsigned d = (lo & 0xffffu) | (hi << 16);
        *(unsigned*)((char*)Pout + (((unsigned)wid) << 7) + loff) = d;
    }
}

// ---------------- batchnorm ----------------

__global__ void bn_stats(const __hip_bfloat16* __restrict__ P, float* __restrict__ acc, int n) {
    int tid = threadIdx.x;
    int c = tid & 15;
    int rowSlot = (int)((blockIdx.x * blockDim.x + tid) >> 4);
    int rowStride = (int)((gridDim.x * blockDim.x) >> 4);
    float s1 = 0.f, s2 = 0.f;
    for (int r = rowSlot; r < n; r += rowStride) {
        const __hip_bfloat16* row = &P[(unsigned)r * 64u];
        float h = (__bfloat162float(row[c]) + __bfloat162float(row[16 + c]) +
                   __bfloat162float(row[32 + c])) * (1.f / 3.f);
        s1 += h;
        s2 += h * h;
    }
    __shared__ float sh[256];
    sh[tid] = s1; __syncthreads();
    for (int off = 128; off >= 16; off >>= 1) { if (tid < off) sh[tid] += sh[tid + off]; __syncthreads(); }
    if (tid < 16) atomicAdd(&acc[tid], sh[tid]);
    __syncthreads();
    sh[tid] = s2; __syncthreads();
    for (int off = 128; off >= 16; off >>= 1) { if (tid < off) sh[tid] += sh[tid + off]; __syncthreads(); }
    if (tid < 16) atomicAdd(&acc[16 + tid], sh[tid]);
}

__global__ void bn_final(const float* acc, const float* g, const float* b,
                         float* coef, int n) {
    int c = threadIdx.x;
    if (c >= 16) return;
    float mu = acc[c] / (float)n;
    float var = acc[16 + c] / (float)n - mu * mu;
    float sc = g[c] / sqrtf(var + 1e-5f);
    coef[c] = sc;
    coef[16 + c] = b[c] - mu * sc;
}

// ---------------- conv2: linear => Horner collapse ----------------

__global__ void cvec_prep(const float* __restrict__ w2w, const float* __restrict__ w2i,
                          const float* __restrict__ w2r, const float* __restrict__ w2b,
                          float* __restrict__ cvec) {
    int c = threadIdx.x;
    float wk0 = w2w[0], wk1 = w2w[1], wk2 = w2w[2];
    const float inv3 = 1.f / 3.f;
    if (c < 16) {
        float psi = 0.f, r3 = 0.f, r2 = 0.f, r1 = 0.f, r0 = 0.f;
        float wks[3] = {wk0, wk1, wk2};
#pragma unroll
        for (int k = 0; k < 3; k++) {
            float w = wks[k], w2_ = w * w, w3 = w2_ * w;
            psi += w3 * w2i[k * 16 + c];
            float rr = w2r[k * 16 + c];
            r3 += w3 * rr; r2 += w2_ * rr; r1 += w * rr; r0 += rr;
        }
        cvec[c] = psi * inv3;
        cvec[16 + c] = r3 * inv3;
        cvec[32 + c] = r2 * inv3;
        cvec[48 + c] = r1 * inv3;
        cvec[64 + c] = r0 * inv3;
    } else if (c == 16) {
        float b3 = 0.f, b2 = 0.f, b1 = 0.f, b0 = 0.f;
        float wks[3] = {wk0, wk1, wk2};
#pragma unroll
        for (int k = 0; k < 3; k++) {
            float w = wks[k], w2_ = w * w, w3 = w2_ * w;
            float b = w2b[k];
            b3 += w3 * b; b2 += w2_ * b; b1 += w * b; b0 += b;
        }
        cvec[80] = b3 * inv3; cvec[81] = b2 * inv3; cvec[82] = b1 * inv3; cvec[83] = b0 * inv3;
    }
}

__global__ void conv2_init(const __hip_bfloat16* __restrict__ P, const float* __restrict__ coef,
                           const float* __restrict__ cvec,
                           float* __restrict__ z, float4* __restrict__ R, int n) {
    unsigned node = blockIdx.x * blockDim.x + threadIdx.x;
    if (node >= (unsigned)n) return;
    const __hip_bfloat16* row = &P[node * 64u];
    float zz = 0.f, r3 = cvec[80], r2 = cvec[81], r1 = cvec[82], r0 = cvec[83];
#pragma unroll
    for (int c = 0; c < 16; c++) {
        float h = (__bfloat162float(row[c]) + __bfloat162float(row[16 + c]) +
                   __bfloat162float(row[32 + c])) * (1.f / 3.f);
        float hb = fmaxf(h * coef[c] + coef[16 + c], 0.f);
        zz += hb * cvec[c];
        r3 += hb * cvec[16 + c];
        r2 += hb * cvec[32 + c];
        r1 += hb * cvec[48 + c];
        r0 += hb * cvec[64 + c];
    }
    z[node] = zz;
    R[node] = make_float4(r3, r2, r1, r0);
}

// Horner step: zout = A*zin + R[:,comp] ; FINAL: out = sigmoid((A*zin + R)*lw + lb)
template<int FINAL>
__global__ void horner(const float* __restrict__ zin, const float* __restrict__ R, int comp,
                       const int* __restrict__ row_ptr, const int2* __restrict__ csr,
                       float* __restrict__ zout, const float* __restrict__ lw,
                       const float* __restrict__ lb, int n) {
    int node = blockIdx.x * blockDim.x + threadIdx.x;
    if (node >= n) return;
    const long long* csr8 = (const long long*)csr;
    int p = row_ptr[node], end = row_ptr[node + 1];
    float a0 = 0.f, a1 = 0.f, a2 = 0.f, a3 = 0.f, a4 = 0.f, a5 = 0.f, a6 = 0.f, a7 = 0.f;
    for (; p + 7 < end; p += 8) {
        long long e0 = __builtin_nontemporal_load(csr8 + p + 0);
        long long e1 = __builtin_nontemporal_load(csr8 + p + 1);
        long long e2 = __builtin_nontemporal_load(csr8 + p + 2);
        long long e3 = __builtin_nontemporal_load(csr8 + p + 3);
        long long e4 = __builtin_nontemporal_load(csr8 + p + 4);
        long long e5 = __builtin_nontemporal_load(csr8 + p + 5);
        long long e6 = __builtin_nontemporal_load(csr8 + p + 6);
        long long e7 = __builtin_nontemporal_load(csr8 + p + 7);
        a0 += zin[(int)e0] * __int_as_float((int)(e0 >> 32));
        a1 += zin[(int)e1] * __int_as_float((int)(e1 >> 32));
        a2 += zin[(int)e2] * __int_as_float((int)(e2 >> 32));
        a3 += zin[(int)e3] * __int_as_float((int)(e3 >> 32));
        a4 += zin[(int)e4] * __int_as_float((int)(e4 >> 32));
        a5 += zin[(int)e5] * __int_as_float((int)(e5 >> 32));
        a6 += zin[(int)e6] * __int_as_float((int)(e6 >> 32));
        a7 += zin[(int)e7] * __int_as_float((int)(e7 >> 32));
    }
    for (; p < end; p++) {
        long long e = __builtin_nontemporal_load(csr8 + p);
        a0 += zin[(int)e] * __int_as_float((int)(e >> 32));
    }
    float v = ((a0 + a1) + (a2 + a3)) + ((a4 + a5) + (a6 + a7)) + R[(unsigned)node * 4u + comp];
    if (FINAL) {
        float t = v * lw[0] + lb[0];
        zout[node] = 1.f / (1.f + expf(-t));
    } else {
        zout[node] = v;
    }
}

// ---------------- launch ----------------

extern "C" void kernel_launch(void* const* d_in, const int* in_sizes, int n_in,
                              void* d_out, int out_size, void* d_ws, size_t ws_size,
                              hipStream_t stream) {
    const float* x = (const float*)d_in[0];
    const int* ei = (const int*)d_in[1];          // int32 per harness convention
    const float* ew = (const float*)d_in[2];
    const float* w1_init = (const float*)d_in[3];
    const float* w1_w = (const float*)d_in[4];
    const float* w1_root = (const float*)d_in[5];
    const float* w1_b = (const float*)d_in[6];
    const float* bn1_g = (const float*)d_in[7];
    const float* bn1_b = (const float*)d_in[8];
    const float* w2_init = (const float*)d_in[9];
    const float* w2_w = (const float*)d_in[10];
    const float* w2_root = (const float*)d_in[11];
    const float* w2_b = (const float*)d_in[12];
    const float* lin_w = (const float*)d_in[13];
    const float* lin_b = (const float*)d_in[14];

    const int N = in_sizes[0];       // 100000
    const int E = in_sizes[2];       // 1600000
    float* out = (float*)d_out;

    // workspace layout (16B-aligned chunks); total ~43 MB
    char* ws = (char*)d_ws;
    size_t off = 0;
    auto alloc = [&](size_t bytes) {
        void* p = ws + off;
        off += (bytes + 15) & ~(size_t)15;
        return p;
    };
    int*   cnt       = (int*)  alloc((size_t)N * 4);
    int*   row_ptr   = (int*)  alloc((size_t)(N + 1) * 4);
    int*   blockSums = (int*)  alloc(128 * 4);
    float* bn_acc    = (float*)alloc(32 * 4);
    float* bn_coef   = (float*)alloc(32 * 4);
    float* cvec      = (float*)alloc(96 * 4);
    float* dis       = (float*)alloc((size_t)N * 4);
    float* y1        = (float*)alloc((size_t)N * 4);
    float* zA        = (float*)alloc((size_t)N * 4);
    float* zB        = (float*)alloc((size_t)N * 4);
    float4* Rbuf     = (float4*)alloc((size_t)N * 16);
    int2*  csr       = (int2*) alloc((size_t)E * 8);
    __hip_bfloat16* bufP = (__hip_bfloat16*)alloc((size_t)N * 64 * 2);
    __hip_bfloat16* bufQ = (__hip_bfloat16*)alloc((size_t)N * 64 * 2);
    int* rank = (int*)bufP;   // overlay: rank[] dead before bufP first written
    (void)ws_size;

    const int BS = 256;
    int gE = (E + BS - 1) / BS;
    int gN = (N + BS - 1) / BS;

    zero_kernel<<<gN, BS, 0, stream>>>((float*)cnt, N);
    zero_kernel<<<1, 32, 0, stream>>>(bn_acc, 32);

    // CSR build: one atomic per edge total
    rank_kernel<<<gE, BS, 0, stream>>>(ei, cnt, rank, E);
    int nb = (N + 1023) / 1024;
    scan1<<<nb, 1024, 0, stream>>>(cnt, row_ptr, blockSums, N);
    scan2<<<1, 64, 0, stream>>>(blockSums, nb);
    scan3<<<nb, 1024, 0, stream>>>(row_ptr, blockSums, N, E);
    place2<<<gE, BS, 0, stream>>>(ei, ew, rank, row_ptr, csr, E);
    wdeg_dis<<<gN, BS, 0, stream>>>(csr, row_ptr, dis, N);
    normk<<<gN, BS, 0, stream>>>(csr, row_ptr, dis, N);

    // ---- conv1 (K=3, H=16, T=4, relu), bf16 features ----
    aggx<<<gN, BS, 0, stream>>>(x, row_ptr, csr, y1, N);
    int g64 = (N * 64 + BS - 1) / BS;
    init48<<<g64, BS, 0, stream>>>(x, y1, w1_init, w1_root, w1_b, bufP, N);
    int gAgg = (N + 3) / 4;  // wave per node
    agg48p<<<gAgg, BS, 0, stream>>>(bufP, w1_w, x, w1_root, w1_b, row_ptr, csr, bufQ, N);
    agg48p<<<gAgg, BS, 0, stream>>>(bufQ, w1_w, x, w1_root, w1_b, row_ptr, csr, bufP, N);
    agg48p<<<gAgg, BS, 0, stream>>>(bufP, w1_w, x, w1_root, w1_b, row_ptr, csr, bufQ, N);
    // conv1 output in bufQ

    // ---- batchnorm (fused coefs) ----
    bn_stats<<<512, 256, 0, stream>>>(bufQ, bn_acc, N);
    bn_final<<<1, 16, 0, stream>>>(bn_acc, bn1_g, bn1_b, bn_coef, N);

    // ---- conv2 collapsed to scalar Horner chain ----
    cvec_prep<<<1, 64, 0, stream>>>(w2_w, w2_init, w2_root, w2_b, cvec);
    conv2_init<<<gN, BS, 0, stream>>>(bufQ, bn_coef, cvec, zA, Rbuf, N);
    horner<0><<<gN, BS, 0, stream>>>(zA, (const float*)Rbuf, 0, row_ptr, csr, zB, lin_w, lin_b, N);
    horner<0><<<gN, BS, 0, stream>>>(zB, (const float*)Rbuf, 1, row_ptr, csr, zA, lin_w, lin_b, N);
    horner<0><<<gN, BS, 0, stream>>>(zA, (const float*)Rbuf, 2, row_ptr, csr, zB, lin_w, lin_b, N);
    horner<1><<<gN, BS, 0, stream>>>(zB, (const float*)Rbuf, 3, row_ptr, csr, out, lin_w, lin_b, N);
}

// Round 6
// 475.551 us; speedup vs baseline: 1.1457x; 1.1457x over previous
//
#include <hip/hip_runtime.h>
#include <hip/hip_bf16.h>
#include <math.h>

// ---------------- setup kernels ----------------

__global__ void zero_kernel(float* p, int n) {
    int i = blockIdx.x * blockDim.x + threadIdx.x;
    if (i < n) p[i] = 0.f;
}

// single-atomic histogram: rank[i] = old count of dst
__global__ void rank_kernel(const int* __restrict__ ei, int* __restrict__ cnt,
                            int* __restrict__ rank, int E) {
    int i = blockIdx.x * blockDim.x + threadIdx.x;
    if (i >= E) return;
    int dst = ei[E + i];
    rank[i] = atomicAdd(&cnt[dst], 1);
}

// --- 3-kernel exclusive scan of cnt -> row_ptr ---
__global__ void scan1(const int* cnt, int* row_ptr, int* blockSums, int n) {
    __shared__ int sh[1024];
    int i = blockIdx.x * 1024 + threadIdx.x;
    int v = (i < n) ? cnt[i] : 0;
    sh[threadIdx.x] = v;
    __syncthreads();
    for (int off = 1; off < 1024; off <<= 1) {
        int t = 0;
        if (threadIdx.x >= off) t = sh[threadIdx.x - off];
        __syncthreads();
        sh[threadIdx.x] += t;
        __syncthreads();
    }
    if (i < n) row_ptr[i] = sh[threadIdx.x] - v;
    if (threadIdx.x == 1023) blockSums[blockIdx.x] = sh[1023];
}

__global__ void scan2(int* blockSums, int nb) {
    if (threadIdx.x == 0 && blockIdx.x == 0) {
        int run = 0;
        for (int i = 0; i < nb; i++) { int v = blockSums[i]; blockSums[i] = run; run += v; }
    }
}

__global__ void scan3(int* row_ptr, const int* blockSums, int n, int E) {
    int i = blockIdx.x * 1024 + threadIdx.x;
    if (i < n) row_ptr[i] += blockSums[blockIdx.x];
    if (i == 0) row_ptr[n] = E;
}

// place edges: pos = row_ptr[dst] + rank[i]; single 8B scattered store (src, ew)
__global__ void place2(const int* __restrict__ ei, const float* __restrict__ ew,
                       const int* __restrict__ rank, const int* __restrict__ row_ptr,
                       int2* __restrict__ csr, int E) {
    int i = blockIdx.x * blockDim.x + threadIdx.x;
    if (i >= E) return;
    int s = ei[i];
    int d = ei[E + i];
    int pos = row_ptr[d] + rank[i];
    csr[pos] = make_int2(s, __float_as_int(ew[i]));
}

// weighted degree from CSR (no atomics) -> dis = 1/sqrt(deg)
__global__ void wdeg_dis(const int2* __restrict__ csr, const int* __restrict__ row_ptr,
                         float* __restrict__ dis, int n) {
    int node = blockIdx.x * blockDim.x + threadIdx.x;
    if (node >= n) return;
    int p = row_ptr[node], end = row_ptr[node + 1];
    float s = 0.f;
    for (; p < end; p++) s += __int_as_float(csr[p].y);
    dis[node] = (s > 0.f) ? (1.0f / sqrtf(s)) : 0.f;
}

// csr.y <- dis[dst]*dis[src]*ew   (in place)
__global__ void normk(int2* __restrict__ csr, const int* __restrict__ row_ptr,
                      const float* __restrict__ dis, int n) {
    int node = blockIdx.x * blockDim.x + threadIdx.x;
    if (node >= n) return;
    int p = row_ptr[node], end = row_ptr[node + 1];
    float dn = dis[node];
    for (; p < end; p++) {
        int2 e = csr[p];
        csr[p].y = __float_as_int(__int_as_float(e.y) * dn * dis[e.x]);
    }
}

// ---------------- conv1 (bf16 features, row stride 64 = 128B) ----------------

// rank-1 collapse of t=0: y[n] = sum_e norm_e * x[src_e]
__global__ void aggx(const float* __restrict__ x, const int* __restrict__ row_ptr,
                     const int2* __restrict__ csr, float* __restrict__ y, int n) {
    int node = blockIdx.x * blockDim.x + threadIdx.x;
    if (node >= n) return;
    const long long* csr8 = (const long long*)csr;
    int p = row_ptr[node], end = row_ptr[node + 1];
    float a0 = 0.f, a1 = 0.f, a2 = 0.f, a3 = 0.f, a4 = 0.f, a5 = 0.f, a6 = 0.f, a7 = 0.f;
    for (; p + 7 < end; p += 8) {
        long long e0 = csr8[p + 0], e1 = csr8[p + 1], e2 = csr8[p + 2], e3 = csr8[p + 3];
        long long e4 = csr8[p + 4], e5 = csr8[p + 5], e6 = csr8[p + 6], e7 = csr8[p + 7];
        a0 += x[(int)e0] * __int_as_float((int)(e0 >> 32));
        a1 += x[(int)e1] * __int_as_float((int)(e1 >> 32));
        a2 += x[(int)e2] * __int_as_float((int)(e2 >> 32));
        a3 += x[(int)e3] * __int_as_float((int)(e3 >> 32));
        a4 += x[(int)e4] * __int_as_float((int)(e4 >> 32));
        a5 += x[(int)e5] * __int_as_float((int)(e5 >> 32));
        a6 += x[(int)e6] * __int_as_float((int)(e6 >> 32));
        a7 += x[(int)e7] * __int_as_float((int)(e7 >> 32));
    }
    for (; p < end; p++) {
        long long e = csr8[p];
        a0 += x[(int)e] * __int_as_float((int)(e >> 32));
    }
    y[node] = ((a0 + a1) + (a2 + a3)) + ((a4 + a5) + (a6 + a7));
}

// out_0 = relu(y*w_init + x*w_root + b), bf16, pad channels 48..63 with 0
__global__ void init48(const float* __restrict__ x, const float* __restrict__ y,
                       const float* __restrict__ w_init, const float* __restrict__ w_root,
                       const float* __restrict__ w_b, __hip_bfloat16* __restrict__ P, int n) {
    unsigned t = blockIdx.x * blockDim.x + threadIdx.x;
    if (t >= (unsigned)n * 64u) return;
    unsigned node = t >> 6, c = t & 63;
    float v = 0.f;
    if (c < 48) v = fmaxf(y[node] * w_init[c] + x[node] * w_root[c] + w_b[c], 0.f);
    P[t] = __float2bfloat16(v);
}

// fused step t>=1: P_out = relu( (A*P_in)*W + x*w_root + b )
// wave per node, lanes 0..47 own channels (2B gather each).
// csr values are wave-uniform -> readfirstlane to SGPRs: gather address is
// SGPR base + lane*2 (saddr form), weight FMA takes an SGPR operand.
__global__ void __launch_bounds__(256) agg48s(
    const __hip_bfloat16* __restrict__ P, const float* __restrict__ W,
    const float* __restrict__ x, const float* __restrict__ w_root,
    const float* __restrict__ w_b, const int* __restrict__ row_ptr,
    const int2* __restrict__ csr, __hip_bfloat16* __restrict__ Pout, int n) {
    int wid = (int)((blockIdx.x * blockDim.x + threadIdx.x) >> 6);
    int lane = threadIdx.x & 63;
    if (wid >= n) return;
    unsigned orow = (unsigned)wid * 64u;
    if (lane >= 48) { Pout[orow + lane] = __float2bfloat16(0.f); return; }
    int k = lane >> 4, o = lane & 15;
    float wv[16];
#pragma unroll
    for (int i = 0; i < 16; i++) wv[i] = W[k * 256 + i * 16 + o];

    const char* Pb = (const char*)P;
    const long long* csr8 = (const long long*)csr;
    unsigned loff = (unsigned)(lane << 1);  // byte offset of channel in row

    int p = row_ptr[wid], end = row_ptr[wid + 1];
    float a0 = 0.f, a1 = 0.f, a2 = 0.f, a3 = 0.f, a4 = 0.f, a5 = 0.f, a6 = 0.f, a7 = 0.f;
    for (; p + 7 < end; p += 8) {
        long long e0 = csr8[p + 0], e1 = csr8[p + 1], e2 = csr8[p + 2], e3 = csr8[p + 3];
        long long e4 = csr8[p + 4], e5 = csr8[p + 5], e6 = csr8[p + 6], e7 = csr8[p + 7];
        int s0 = __builtin_amdgcn_readfirstlane((int)e0);
        int s1 = __builtin_amdgcn_readfirstlane((int)e1);
        int s2 = __builtin_amdgcn_readfirstlane((int)e2);
        int s3 = __builtin_amdgcn_readfirstlane((int)e3);
        int s4 = __builtin_amdgcn_readfirstlane((int)e4);
        int s5 = __builtin_amdgcn_readfirstlane((int)e5);
        int s6 = __builtin_amdgcn_readfirstlane((int)e6);
        int s7 = __builtin_amdgcn_readfirstlane((int)e7);
        float w0 = __int_as_float(__builtin_amdgcn_readfirstlane((int)(e0 >> 32)));
        float w1 = __int_as_float(__builtin_amdgcn_readfirstlane((int)(e1 >> 32)));
        float w2 = __int_as_float(__builtin_amdgcn_readfirstlane((int)(e2 >> 32)));
        float w3 = __int_as_float(__builtin_amdgcn_readfirstlane((int)(e3 >> 32)));
        float w4 = __int_as_float(__builtin_amdgcn_readfirstlane((int)(e4 >> 32)));
        float w5 = __int_as_float(__builtin_amdgcn_readfirstlane((int)(e5 >> 32)));
        float w6 = __int_as_float(__builtin_amdgcn_readfirstlane((int)(e6 >> 32)));
        float w7 = __int_as_float(__builtin_amdgcn_readfirstlane((int)(e7 >> 32)));
        unsigned short u0 = *(const unsigned short*)(Pb + (((unsigned)s0) << 7) + loff);
        unsigned short u1 = *(const unsigned short*)(Pb + (((unsigned)s1) << 7) + loff);
        unsigned short u2 = *(const unsigned short*)(Pb + (((unsigned)s2) << 7) + loff);
        unsigned short u3 = *(const unsigned short*)(Pb + (((unsigned)s3) << 7) + loff);
        unsigned short u4 = *(const unsigned short*)(Pb + (((unsigned)s4) << 7) + loff);
        unsigned short u5 = *(const unsigned short*)(Pb + (((unsigned)s5) << 7) + loff);
        unsigned short u6 = *(const unsigned short*)(Pb + (((unsigned)s6) << 7) + loff);
        unsigned short u7 = *(const unsigned short*)(Pb + (((unsigned)s7) << 7) + loff);
        a0 += __int_as_float(((unsigned)u0) << 16) * w0;
        a1 += __int_as_float(((unsigned)u1) << 16) * w1;
        a2 += __int_as_float(((unsigned)u2) << 16) * w2;
        a3 += __int_as_float(((unsigned)u3) << 16) * w3;
        a4 += __int_as_float(((unsigned)u4) << 16) * w4;
        a5 += __int_as_float(((unsigned)u5) << 16) * w5;
        a6 += __int_as_float(((unsigned)u6) << 16) * w6;
        a7 += __int_as_float(((unsigned)u7) << 16) * w7;
    }
    for (; p < end; p++) {
        long long e = csr8[p];
        int s = __builtin_amdgcn_readfirstlane((int)e);
        float w = __int_as_float(__builtin_amdgcn_readfirstlane((int)(e >> 32)));
        unsigned short u = *(const unsigned short*)(Pb + (((unsigned)s) << 7) + loff);
        a0 += __int_as_float(((unsigned)u) << 16) * w;
    }
    float S = ((a0 + a1) + (a2 + a3)) + ((a4 + a5) + (a6 + a7));

    // in-register 16x16 transform: out[o] = sum_i S[i] * W[k][i][o]
    float acc = 0.f;
    int base = lane & 48;  // k*16
#pragma unroll
    for (int i = 0; i < 16; i++) {
        float sv = __shfl(S, base + i, 64);
        acc += sv * wv[i];
    }
    float v = acc + x[wid] * w_root[lane] + w_b[lane];
    Pout[orow + lane] = __float2bfloat16(fmaxf(v, 0.f));
}

// ---------------- batchnorm ----------------

__global__ void bn_stats(const __hip_bfloat16* __restrict__ P, float* __restrict__ acc, int n) {
    int tid = threadIdx.x;
    int c = tid & 15;
    int rowSlot = (int)((blockIdx.x * blockDim.x + tid) >> 4);
    int rowStride = (int)((gridDim.x * blockDim.x) >> 4);
    float s1 = 0.f, s2 = 0.f;
    for (int r = rowSlot; r < n; r += rowStride) {
        const __hip_bfloat16* row = &P[(unsigned)r * 64u];
        float h = (__bfloat162float(row[c]) + __bfloat162float(row[16 + c]) +
                   __bfloat162float(row[32 + c])) * (1.f / 3.f);
        s1 += h;
        s2 += h * h;
    }
    __shared__ float sh[256];
    sh[tid] = s1; __syncthreads();
    for (int off = 128; off >= 16; off >>= 1) { if (tid < off) sh[tid] += sh[tid + off]; __syncthreads(); }
    if (tid < 16) atomicAdd(&acc[tid], sh[tid]);
    __syncthreads();
    sh[tid] = s2; __syncthreads();
    for (int off = 128; off >= 16; off >>= 1) { if (tid < off) sh[tid] += sh[tid + off]; __syncthreads(); }
    if (tid < 16) atomicAdd(&acc[16 + tid], sh[tid]);
}

__global__ void bn_final(const float* acc, const float* g, const float* b,
                         float* coef, int n) {
    int c = threadIdx.x;
    if (c >= 16) return;
    float mu = acc[c] / (float)n;
    float var = acc[16 + c] / (float)n - mu * mu;
    float sc = g[c] / sqrtf(var + 1e-5f);
    coef[c] = sc;
    coef[16 + c] = b[c] - mu * sc;
}

// ---------------- conv2: linear => Horner collapse ----------------

__global__ void cvec_prep(const float* __restrict__ w2w, const float* __restrict__ w2i,
                          const float* __restrict__ w2r, const float* __restrict__ w2b,
                          float* __restrict__ cvec) {
    int c = threadIdx.x;
    float wk0 = w2w[0], wk1 = w2w[1], wk2 = w2w[2];
    const float inv3 = 1.f / 3.f;
    if (c < 16) {
        float psi = 0.f, r3 = 0.f, r2 = 0.f, r1 = 0.f, r0 = 0.f;
        float wks[3] = {wk0, wk1, wk2};
#pragma unroll
        for (int k = 0; k < 3; k++) {
            float w = wks[k], w2_ = w * w, w3 = w2_ * w;
            psi += w3 * w2i[k * 16 + c];
            float rr = w2r[k * 16 + c];
            r3 += w3 * rr; r2 += w2_ * rr; r1 += w * rr; r0 += rr;
        }
        cvec[c] = psi * inv3;
        cvec[16 + c] = r3 * inv3;
        cvec[32 + c] = r2 * inv3;
        cvec[48 + c] = r1 * inv3;
        cvec[64 + c] = r0 * inv3;
    } else if (c == 16) {
        float b3 = 0.f, b2 = 0.f, b1 = 0.f, b0 = 0.f;
        float wks[3] = {wk0, wk1, wk2};
#pragma unroll
        for (int k = 0; k < 3; k++) {
            float w = wks[k], w2_ = w * w, w3 = w2_ * w;
            float b = w2b[k];
            b3 += w3 * b; b2 += w2_ * b; b1 += w * b; b0 += b;
        }
        cvec[80] = b3 * inv3; cvec[81] = b2 * inv3; cvec[82] = b1 * inv3; cvec[83] = b0 * inv3;
    }
}

__global__ void conv2_init(const __hip_bfloat16* __restrict__ P, const float* __restrict__ coef,
                           const float* __restrict__ cvec,
                           float* __restrict__ z, float4* __restrict__ R, int n) {
    unsigned node = blockIdx.x * blockDim.x + threadIdx.x;
    if (node >= (unsigned)n) return;
    const __hip_bfloat16* row = &P[node * 64u];
    float zz = 0.f, r3 = cvec[80], r2 = cvec[81], r1 = cvec[82], r0 = cvec[83];
#pragma unroll
    for (int c = 0; c < 16; c++) {
        float h = (__bfloat162float(row[c]) + __bfloat162float(row[16 + c]) +
                   __bfloat162float(row[32 + c])) * (1.f / 3.f);
        float hb = fmaxf(h * coef[c] + coef[16 + c], 0.f);
        zz += hb * cvec[c];
        r3 += hb * cvec[16 + c];
        r2 += hb * cvec[32 + c];
        r1 += hb * cvec[48 + c];
        r0 += hb * cvec[64 + c];
    }
    z[node] = zz;
    R[node] = make_float4(r3, r2, r1, r0);
}

// Horner step: zout = A*zin + R[:,comp] ; FINAL: out = sigmoid((A*zin + R)*lw + lb)
template<int FINAL>
__global__ void horner(const float* __restrict__ zin, const float* __restrict__ R, int comp,
                       const int* __restrict__ row_ptr, const int2* __restrict__ csr,
                       float* __restrict__ zout, const float* __restrict__ lw,
                       const float* __restrict__ lb, int n) {
    int node = blockIdx.x * blockDim.x + threadIdx.x;
    if (node >= n) return;
    const long long* csr8 = (const long long*)csr;
    int p = row_ptr[node], end = row_ptr[node + 1];
    float a0 = 0.f, a1 = 0.f, a2 = 0.f, a3 = 0.f, a4 = 0.f, a5 = 0.f, a6 = 0.f, a7 = 0.f;
    for (; p + 7 < end; p += 8) {
        long long e0 = csr8[p + 0], e1 = csr8[p + 1], e2 = csr8[p + 2], e3 = csr8[p + 3];
        long long e4 = csr8[p + 4], e5 = csr8[p + 5], e6 = csr8[p + 6], e7 = csr8[p + 7];
        a0 += zin[(int)e0] * __int_as_float((int)(e0 >> 32));
        a1 += zin[(int)e1] * __int_as_float((int)(e1 >> 32));
        a2 += zin[(int)e2] * __int_as_float((int)(e2 >> 32));
        a3 += zin[(int)e3] * __int_as_float((int)(e3 >> 32));
        a4 += zin[(int)e4] * __int_as_float((int)(e4 >> 32));
        a5 += zin[(int)e5] * __int_as_float((int)(e5 >> 32));
        a6 += zin[(int)e6] * __int_as_float((int)(e6 >> 32));
        a7 += zin[(int)e7] * __int_as_float((int)(e7 >> 32));
    }
    for (; p < end; p++) {
        long long e = csr8[p];
        a0 += zin[(int)e] * __int_as_float((int)(e >> 32));
    }
    float v = ((a0 + a1) + (a2 + a3)) + ((a4 + a5) + (a6 + a7)) + R[(unsigned)node * 4u + comp];
    if (FINAL) {
        float t = v * lw[0] + lb[0];
        zout[node] = 1.f / (1.f + expf(-t));
    } else {
        zout[node] = v;
    }
}

// ---------------- launch ----------------

extern "C" void kernel_launch(void* const* d_in, const int* in_sizes, int n_in,
                              void* d_out, int out_size, void* d_ws, size_t ws_size,
                              hipStream_t stream) {
    const float* x = (const float*)d_in[0];
    const int* ei = (const int*)d_in[1];          // int32 per harness convention
    const float* ew = (const float*)d_in[2];
    const float* w1_init = (const float*)d_in[3];
    const float* w1_w = (const float*)d_in[4];
    const float* w1_root = (const float*)d_in[5];
    const float* w1_b = (const float*)d_in[6];
    const float* bn1_g = (const float*)d_in[7];
    const float* bn1_b = (const float*)d_in[8];
    const float* w2_init = (const float*)d_in[9];
    const float* w2_w = (const float*)d_in[10];
    const float* w2_root = (const float*)d_in[11];
    const float* w2_b = (const float*)d_in[12];
    const float* lin_w = (const float*)d_in[13];
    const float* lin_b = (const float*)d_in[14];

    const int N = in_sizes[0];       // 100000
    const int E = in_sizes[2];       // 1600000
    float* out = (float*)d_out;

    // workspace layout (16B-aligned chunks); total ~43 MB
    char* ws = (char*)d_ws;
    size_t off = 0;
    auto alloc = [&](size_t bytes) {
        void* p = ws + off;
        off += (bytes + 15) & ~(size_t)15;
        return p;
    };
    int*   cnt       = (int*)  alloc((size_t)N * 4);
    int*   row_ptr   = (int*)  alloc((size_t)(N + 1) * 4);
    int*   blockSums = (int*)  alloc(128 * 4);
    float* bn_acc    = (float*)alloc(32 * 4);
    float* bn_coef   = (float*)alloc(32 * 4);
    float* cvec      = (float*)alloc(96 * 4);
    float* dis       = (float*)alloc((size_t)N * 4);
    float* y1        = (float*)alloc((size_t)N * 4);
    float* zA        = (float*)alloc((size_t)N * 4);
    float* zB        = (float*)alloc((size_t)N * 4);
    float4* Rbuf     = (float4*)alloc((size_t)N * 16);
    int2*  csr       = (int2*) alloc((size_t)E * 8);
    __hip_bfloat16* bufP = (__hip_bfloat16*)alloc((size_t)N * 64 * 2);
    __hip_bfloat16* bufQ = (__hip_bfloat16*)alloc((size_t)N * 64 * 2);
    int* rank = (int*)bufP;   // overlay: rank[] dead before bufP first written
    (void)ws_size;

    const int BS = 256;
    int gE = (E + BS - 1) / BS;
    int gN = (N + BS - 1) / BS;

    zero_kernel<<<gN, BS, 0, stream>>>((float*)cnt, N);
    zero_kernel<<<1, 32, 0, stream>>>(bn_acc, 32);

    // CSR build: one atomic per edge total
    rank_kernel<<<gE, BS, 0, stream>>>(ei, cnt, rank, E);
    int nb = (N + 1023) / 1024;
    scan1<<<nb, 1024, 0, stream>>>(cnt, row_ptr, blockSums, N);
    scan2<<<1, 64, 0, stream>>>(blockSums, nb);
    scan3<<<nb, 1024, 0, stream>>>(row_ptr, blockSums, N, E);
    place2<<<gE, BS, 0, stream>>>(ei, ew, rank, row_ptr, csr, E);
    wdeg_dis<<<gN, BS, 0, stream>>>(csr, row_ptr, dis, N);
    normk<<<gN, BS, 0, stream>>>(csr, row_ptr, dis, N);

    // ---- conv1 (K=3, H=16, T=4, relu), bf16 features ----
    aggx<<<gN, BS, 0, stream>>>(x, row_ptr, csr, y1, N);
    int g64 = (N * 64 + BS - 1) / BS;
    init48<<<g64, BS, 0, stream>>>(x, y1, w1_init, w1_root, w1_b, bufP, N);
    int gAgg = (N + 3) / 4;  // wave per node
    agg48s<<<gAgg, BS, 0, stream>>>(bufP, w1_w, x, w1_root, w1_b, row_ptr, csr, bufQ, N);
    agg48s<<<gAgg, BS, 0, stream>>>(bufQ, w1_w, x, w1_root, w1_b, row_ptr, csr, bufP, N);
    agg48s<<<gAgg, BS, 0, stream>>>(bufP, w1_w, x, w1_root, w1_b, row_ptr, csr, bufQ, N);
    // conv1 output in bufQ

    // ---- batchnorm (fused coefs) ----
    bn_stats<<<512, 256, 0, stream>>>(bufQ, bn_acc, N);
    bn_final<<<1, 16, 0, stream>>>(bn_acc, bn1_g, bn1_b, bn_coef, N);

    // ---- conv2 collapsed to scalar Horner chain ----
    cvec_prep<<<1, 64, 0, stream>>>(w2_w, w2_init, w2_root, w2_b, cvec);
    conv2_init<<<gN, BS, 0, stream>>>(bufQ, bn_coef, cvec, zA, Rbuf, N);
    horner<0><<<gN, BS, 0, stream>>>(zA, (const float*)Rbuf, 0, row_ptr, csr, zB, lin_w, lin_b, N);
    horner<0><<<gN, BS, 0, stream>>>(zB, (const float*)Rbuf, 1, row_ptr, csr, zA, lin_w, lin_b, N);
    horner<0><<<gN, BS, 0, stream>>>(zA, (const float*)Rbuf, 2, row_ptr, csr, zB, lin_w, lin_b, N);
    horner<1><<<gN, BS, 0, stream>>>(zB, (const float*)Rbuf, 3, row_ptr, csr, out, lin_w, lin_b, N);
}

// Round 7
// 438.261 us; speedup vs baseline: 1.2432x; 1.0851x over previous
//
#include <hip/hip_runtime.h>
#include <hip/hip_bf16.h>
#include <math.h>

// ---------------- setup kernels ----------------

__global__ void zero_kernel(float* p, int n) {
    int i = blockIdx.x * blockDim.x + threadIdx.x;
    if (i < n) p[i] = 0.f;
}

// single-atomic histogram: rank[i] = old count of dst
__global__ void rank_kernel(const int* __restrict__ ei, int* __restrict__ cnt,
                            int* __restrict__ rank, int E) {
    int i = blockIdx.x * blockDim.x + threadIdx.x;
    if (i >= E) return;
    int dst = ei[E + i];
    rank[i] = atomicAdd(&cnt[dst], 1);
}

// --- 3-kernel exclusive scan of cnt -> row_ptr ---
__global__ void scan1(const int* cnt, int* row_ptr, int* blockSums, int n) {
    __shared__ int sh[1024];
    int i = blockIdx.x * 1024 + threadIdx.x;
    int v = (i < n) ? cnt[i] : 0;
    sh[threadIdx.x] = v;
    __syncthreads();
    for (int off = 1; off < 1024; off <<= 1) {
        int t = 0;
        if (threadIdx.x >= off) t = sh[threadIdx.x - off];
        __syncthreads();
        sh[threadIdx.x] += t;
        __syncthreads();
    }
    if (i < n) row_ptr[i] = sh[threadIdx.x] - v;
    if (threadIdx.x == 1023) blockSums[blockIdx.x] = sh[1023];
}

__global__ void scan2(int* blockSums, int nb) {
    if (threadIdx.x == 0 && blockIdx.x == 0) {
        int run = 0;
        for (int i = 0; i < nb; i++) { int v = blockSums[i]; blockSums[i] = run; run += v; }
    }
}

__global__ void scan3(int* row_ptr, const int* blockSums, int n, int E) {
    int i = blockIdx.x * 1024 + threadIdx.x;
    if (i < n) row_ptr[i] += blockSums[blockIdx.x];
    if (i == 0) row_ptr[n] = E;
}

// place edges: pos = row_ptr[dst] + rank[i]; single 8B scattered store (src, ew)
__global__ void place2(const int* __restrict__ ei, const float* __restrict__ ew,
                       const int* __restrict__ rank, const int* __restrict__ row_ptr,
                       int2* __restrict__ csr, int E) {
    int i = blockIdx.x * blockDim.x + threadIdx.x;
    if (i >= E) return;
    int s = ei[i];
    int d = ei[E + i];
    int pos = row_ptr[d] + rank[i];
    csr[pos] = make_int2(s, __float_as_int(ew[i]));
}

// weighted degree from CSR (no atomics) -> dis = 1/sqrt(deg)
__global__ void wdeg_dis(const int2* __restrict__ csr, const int* __restrict__ row_ptr,
                         float* __restrict__ dis, int n) {
    int node = blockIdx.x * blockDim.x + threadIdx.x;
    if (node >= n) return;
    int p = row_ptr[node], end = row_ptr[node + 1];
    float s = 0.f;
    for (; p < end; p++) s += __int_as_float(csr[p].y);
    dis[node] = (s > 0.f) ? (1.0f / sqrtf(s)) : 0.f;
}

// csr.y <- dis[dst]*dis[src]*ew   (in place)
__global__ void normk(int2* __restrict__ csr, const int* __restrict__ row_ptr,
                      const float* __restrict__ dis, int n) {
    int node = blockIdx.x * blockDim.x + threadIdx.x;
    if (node >= n) return;
    int p = row_ptr[node], end = row_ptr[node + 1];
    float dn = dis[node];
    for (; p < end; p++) {
        int2 e = csr[p];
        csr[p].y = __float_as_int(__int_as_float(e.y) * dn * dis[e.x]);
    }
}

// ---------------- conv1 (bf16 features, row stride 64 = 128B) ----------------

// rank-1 collapse of t=0: y[n] = sum_e norm_e * x[src_e]  (unroll 16, phased)
__global__ void aggx(const float* __restrict__ x, const int* __restrict__ row_ptr,
                     const int2* __restrict__ csr, float* __restrict__ y, int n) {
    int node = blockIdx.x * blockDim.x + threadIdx.x;
    if (node >= n) return;
    const long long* csr8 = (const long long*)csr;
    int p = row_ptr[node], end = row_ptr[node + 1];
    float a0 = 0.f, a1 = 0.f, a2 = 0.f, a3 = 0.f, a4 = 0.f, a5 = 0.f, a6 = 0.f, a7 = 0.f;
    for (; p + 15 < end; p += 16) {
        long long e[16];
#pragma unroll
        for (int j = 0; j < 16; j++) e[j] = csr8[p + j];
        float q[16];
#pragma unroll
        for (int j = 0; j < 16; j++) q[j] = x[(int)e[j]];
#pragma unroll
        for (int j = 0; j < 8; j++) {
            a0 += q[2 * j] * __int_as_float((int)(e[2 * j] >> 32));
            a1 += q[2 * j + 1] * __int_as_float((int)(e[2 * j + 1] >> 32));
        }
    }
    for (; p + 7 < end; p += 8) {
        long long e[8];
#pragma unroll
        for (int j = 0; j < 8; j++) e[j] = csr8[p + j];
#pragma unroll
        for (int j = 0; j < 8; j++) {
            float q = x[(int)e[j]];
            (j & 1 ? a1 : a0) += q * __int_as_float((int)(e[j] >> 32));
        }
    }
    for (; p < end; p++) {
        long long e = csr8[p];
        a0 += x[(int)e] * __int_as_float((int)(e >> 32));
    }
    y[node] = ((a0 + a1) + (a2 + a3)) + ((a4 + a5) + (a6 + a7));
}

// out_0 = relu(y*w_init + x*w_root + b), bf16, pad channels 48..63 with 0
__global__ void init48(const float* __restrict__ x, const float* __restrict__ y,
                       const float* __restrict__ w_init, const float* __restrict__ w_root,
                       const float* __restrict__ w_b, __hip_bfloat16* __restrict__ P, int n) {
    unsigned t = blockIdx.x * blockDim.x + threadIdx.x;
    if (t >= (unsigned)n * 64u) return;
    unsigned node = t >> 6, c = t & 63;
    float v = 0.f;
    if (c < 48) v = fmaxf(y[node] * w_init[c] + x[node] * w_root[c] + w_b[c], 0.f);
    P[t] = __float2bfloat16(v);
}

// fused step t>=1: P_out = relu( (A*P_in)*W + x*w_root + b )
// wave per node, lanes 0..47 own channels; 16-edge phased unroll:
// issue 16 csr loads, then 16 gathers, then FMAs — maximizes loads in flight.
__global__ void __launch_bounds__(256) agg48u(
    const __hip_bfloat16* __restrict__ P, const float* __restrict__ W,
    const float* __restrict__ x, const float* __restrict__ w_root,
    const float* __restrict__ w_b, const int* __restrict__ row_ptr,
    const int2* __restrict__ csr, __hip_bfloat16* __restrict__ Pout, int n) {
    int wid = (int)((blockIdx.x * blockDim.x + threadIdx.x) >> 6);
    int lane = threadIdx.x & 63;
    if (wid >= n) return;
    unsigned orow = (unsigned)wid * 64u;
    if (lane >= 48) { Pout[orow + lane] = __float2bfloat16(0.f); return; }
    int k = lane >> 4, o = lane & 15;
    float wv[16];
#pragma unroll
    for (int i = 0; i < 16; i++) wv[i] = W[k * 256 + i * 16 + o];

    const long long* csr8 = (const long long*)csr;
    int p = row_ptr[wid], end = row_ptr[wid + 1];
    float a0 = 0.f, a1 = 0.f, a2 = 0.f, a3 = 0.f;
    // 16-edge main body
    for (; p + 15 < end; p += 16) {
        long long e[16];
#pragma unroll
        for (int j = 0; j < 16; j++) e[j] = csr8[p + j];
        float q[16];
#pragma unroll
        for (int j = 0; j < 16; j++)
            q[j] = __bfloat162float(P[(unsigned)(int)e[j] * 64u + lane]);
#pragma unroll
        for (int j = 0; j < 4; j++) {
            a0 += q[4 * j]     * __int_as_float((int)(e[4 * j]     >> 32));
            a1 += q[4 * j + 1] * __int_as_float((int)(e[4 * j + 1] >> 32));
            a2 += q[4 * j + 2] * __int_as_float((int)(e[4 * j + 2] >> 32));
            a3 += q[4 * j + 3] * __int_as_float((int)(e[4 * j + 3] >> 32));
        }
    }
    // 8-edge body
    for (; p + 7 < end; p += 8) {
        long long e[8];
#pragma unroll
        for (int j = 0; j < 8; j++) e[j] = csr8[p + j];
        float q[8];
#pragma unroll
        for (int j = 0; j < 8; j++)
            q[j] = __bfloat162float(P[(unsigned)(int)e[j] * 64u + lane]);
#pragma unroll
        for (int j = 0; j < 2; j++) {
            a0 += q[4 * j]     * __int_as_float((int)(e[4 * j]     >> 32));
            a1 += q[4 * j + 1] * __int_as_float((int)(e[4 * j + 1] >> 32));
            a2 += q[4 * j + 2] * __int_as_float((int)(e[4 * j + 2] >> 32));
            a3 += q[4 * j + 3] * __int_as_float((int)(e[4 * j + 3] >> 32));
        }
    }
    // 4-edge body
    for (; p + 3 < end; p += 4) {
        long long e[4];
#pragma unroll
        for (int j = 0; j < 4; j++) e[j] = csr8[p + j];
#pragma unroll
        for (int j = 0; j < 4; j++) {
            float q = __bfloat162float(P[(unsigned)(int)e[j] * 64u + lane]);
            (j == 0 ? a0 : j == 1 ? a1 : j == 2 ? a2 : a3) += q * __int_as_float((int)(e[j] >> 32));
        }
    }
    for (; p < end; p++) {
        long long e = csr8[p];
        a0 += __bfloat162float(P[(unsigned)(int)e * 64u + lane]) * __int_as_float((int)(e >> 32));
    }
    float S = (a0 + a1) + (a2 + a3);

    // in-register 16x16 transform: out[o] = sum_i S[i] * W[k][i][o]
    float acc = 0.f;
    int base = lane & 48;  // k*16
#pragma unroll
    for (int i = 0; i < 16; i++) {
        float sv = __shfl(S, base + i, 64);
        acc += sv * wv[i];
    }
    float v = acc + x[wid] * w_root[lane] + w_b[lane];
    Pout[orow + lane] = __float2bfloat16(fmaxf(v, 0.f));
}

// ---------------- batchnorm ----------------

__global__ void bn_stats(const __hip_bfloat16* __restrict__ P, float* __restrict__ acc, int n) {
    int tid = threadIdx.x;
    int c = tid & 15;
    int rowSlot = (int)((blockIdx.x * blockDim.x + tid) >> 4);
    int rowStride = (int)((gridDim.x * blockDim.x) >> 4);
    float s1 = 0.f, s2 = 0.f;
    for (int r = rowSlot; r < n; r += rowStride) {
        const __hip_bfloat16* row = &P[(unsigned)r * 64u];
        float h = (__bfloat162float(row[c]) + __bfloat162float(row[16 + c]) +
                   __bfloat162float(row[32 + c])) * (1.f / 3.f);
        s1 += h;
        s2 += h * h;
    }
    __shared__ float sh[256];
    sh[tid] = s1; __syncthreads();
    for (int off = 128; off >= 16; off >>= 1) { if (tid < off) sh[tid] += sh[tid + off]; __syncthreads(); }
    if (tid < 16) atomicAdd(&acc[tid], sh[tid]);
    __syncthreads();
    sh[tid] = s2; __syncthreads();
    for (int off = 128; off >= 16; off >>= 1) { if (tid < off) sh[tid] += sh[tid + off]; __syncthreads(); }
    if (tid < 16) atomicAdd(&acc[16 + tid], sh[tid]);
}

__global__ void bn_final(const float* acc, const float* g, const float* b,
                         float* coef, int n) {
    int c = threadIdx.x;
    if (c >= 16) return;
    float mu = acc[c] / (float)n;
    float var = acc[16 + c] / (float)n - mu * mu;
    float sc = g[c] / sqrtf(var + 1e-5f);
    coef[c] = sc;
    coef[16 + c] = b[c] - mu * sc;
}

// ---------------- conv2: linear => Horner collapse ----------------

__global__ void cvec_prep(const float* __restrict__ w2w, const float* __restrict__ w2i,
                          const float* __restrict__ w2r, const float* __restrict__ w2b,
                          float* __restrict__ cvec) {
    int c = threadIdx.x;
    float wk0 = w2w[0], wk1 = w2w[1], wk2 = w2w[2];
    const float inv3 = 1.f / 3.f;
    if (c < 16) {
        float psi = 0.f, r3 = 0.f, r2 = 0.f, r1 = 0.f, r0 = 0.f;
        float wks[3] = {wk0, wk1, wk2};
#pragma unroll
        for (int k = 0; k < 3; k++) {
            float w = wks[k], w2_ = w * w, w3 = w2_ * w;
            psi += w3 * w2i[k * 16 + c];
            float rr = w2r[k * 16 + c];
            r3 += w3 * rr; r2 += w2_ * rr; r1 += w * rr; r0 += rr;
        }
        cvec[c] = psi * inv3;
        cvec[16 + c] = r3 * inv3;
        cvec[32 + c] = r2 * inv3;
        cvec[48 + c] = r1 * inv3;
        cvec[64 + c] = r0 * inv3;
    } else if (c == 16) {
        float b3 = 0.f, b2 = 0.f, b1 = 0.f, b0 = 0.f;
        float wks[3] = {wk0, wk1, wk2};
#pragma unroll
        for (int k = 0; k < 3; k++) {
            float w = wks[k], w2_ = w * w, w3 = w2_ * w;
            float b = w2b[k];
            b3 += w3 * b; b2 += w2_ * b; b1 += w * b; b0 += b;
        }
        cvec[80] = b3 * inv3; cvec[81] = b2 * inv3; cvec[82] = b1 * inv3; cvec[83] = b0 * inv3;
    }
}

__global__ void conv2_init(const __hip_bfloat16* __restrict__ P, const float* __restrict__ coef,
                           const float* __restrict__ cvec,
                           float* __restrict__ z, float4* __restrict__ R, int n) {
    unsigned node = blockIdx.x * blockDim.x + threadIdx.x;
    if (node >= (unsigned)n) return;
    const __hip_bfloat16* row = &P[node * 64u];
    float zz = 0.f, r3 = cvec[80], r2 = cvec[81], r1 = cvec[82], r0 = cvec[83];
#pragma unroll
    for (int c = 0; c < 16; c++) {
        float h = (__bfloat162float(row[c]) + __bfloat162float(row[16 + c]) +
                   __bfloat162float(row[32 + c])) * (1.f / 3.f);
        float hb = fmaxf(h * coef[c] + coef[16 + c], 0.f);
        zz += hb * cvec[c];
        r3 += hb * cvec[16 + c];
        r2 += hb * cvec[32 + c];
        r1 += hb * cvec[48 + c];
        r0 += hb * cvec[64 + c];
    }
    z[node] = zz;
    R[node] = make_float4(r3, r2, r1, r0);
}

// Horner step: zout = A*zin + R[:,comp] ; FINAL: out = sigmoid((A*zin + R)*lw + lb)
template<int FINAL>
__global__ void horner(const float* __restrict__ zin, const float* __restrict__ R, int comp,
                       const int* __restrict__ row_ptr, const int2* __restrict__ csr,
                       float* __restrict__ zout, const float* __restrict__ lw,
                       const float* __restrict__ lb, int n) {
    int node = blockIdx.x * blockDim.x + threadIdx.x;
    if (node >= n) return;
    const long long* csr8 = (const long long*)csr;
    int p = row_ptr[node], end = row_ptr[node + 1];
    float a0 = 0.f, a1 = 0.f;
    for (; p + 15 < end; p += 16) {
        long long e[16];
#pragma unroll
        for (int j = 0; j < 16; j++) e[j] = csr8[p + j];
        float q[16];
#pragma unroll
        for (int j = 0; j < 16; j++) q[j] = zin[(int)e[j]];
#pragma unroll
        for (int j = 0; j < 8; j++) {
            a0 += q[2 * j] * __int_as_float((int)(e[2 * j] >> 32));
            a1 += q[2 * j + 1] * __int_as_float((int)(e[2 * j + 1] >> 32));
        }
    }
    for (; p + 7 < end; p += 8) {
        long long e[8];
#pragma unroll
        for (int j = 0; j < 8; j++) e[j] = csr8[p + j];
#pragma unroll
        for (int j = 0; j < 8; j++) {
            float q = zin[(int)e[j]];
            (j & 1 ? a1 : a0) += q * __int_as_float((int)(e[j] >> 32));
        }
    }
    for (; p < end; p++) {
        long long e = csr8[p];
        a0 += zin[(int)e] * __int_as_float((int)(e >> 32));
    }
    float v = (a0 + a1) + R[(unsigned)node * 4u + comp];
    if (FINAL) {
        float t = v * lw[0] + lb[0];
        zout[node] = 1.f / (1.f + expf(-t));
    } else {
        zout[node] = v;
    }
}

// ---------------- launch ----------------

extern "C" void kernel_launch(void* const* d_in, const int* in_sizes, int n_in,
                              void* d_out, int out_size, void* d_ws, size_t ws_size,
                              hipStream_t stream) {
    const float* x = (const float*)d_in[0];
    const int* ei = (const int*)d_in[1];          // int32 per harness convention
    const float* ew = (const float*)d_in[2];
    const float* w1_init = (const float*)d_in[3];
    const float* w1_w = (const float*)d_in[4];
    const float* w1_root = (const float*)d_in[5];
    const float* w1_b = (const float*)d_in[6];
    const float* bn1_g = (const float*)d_in[7];
    const float* bn1_b = (const float*)d_in[8];
    const float* w2_init = (const float*)d_in[9];
    const float* w2_w = (const float*)d_in[10];
    const float* w2_root = (const float*)d_in[11];
    const float* w2_b = (const float*)d_in[12];
    const float* lin_w = (const float*)d_in[13];
    const float* lin_b = (const float*)d_in[14];

    const int N = in_sizes[0];       // 100000
    const int E = in_sizes[2];       // 1600000
    float* out = (float*)d_out;

    // workspace layout (16B-aligned chunks); total ~43 MB
    char* ws = (char*)d_ws;
    size_t off = 0;
    auto alloc = [&](size_t bytes) {
        void* p = ws + off;
        off += (bytes + 15) & ~(size_t)15;
        return p;
    };
    int*   cnt       = (int*)  alloc((size_t)N * 4);
    int*   row_ptr   = (int*)  alloc((size_t)(N + 1) * 4);
    int*   blockSums = (int*)  alloc(128 * 4);
    float* bn_acc    = (float*)alloc(32 * 4);
    float* bn_coef   = (float*)alloc(32 * 4);
    float* cvec      = (float*)alloc(96 * 4);
    float* dis       = (float*)alloc((size_t)N * 4);
    float* y1        = (float*)alloc((size_t)N * 4);
    float* zA        = (float*)alloc((size_t)N * 4);
    float* zB        = (float*)alloc((size_t)N * 4);
    float4* Rbuf     = (float4*)alloc((size_t)N * 16);
    int2*  csr       = (int2*) alloc((size_t)E * 8);
    __hip_bfloat16* bufP = (__hip_bfloat16*)alloc((size_t)N * 64 * 2);
    __hip_bfloat16* bufQ = (__hip_bfloat16*)alloc((size_t)N * 64 * 2);
    int* rank = (int*)bufP;   // overlay: rank[] dead before bufP first written
    (void)ws_size;

    const int BS = 256;
    int gE = (E + BS - 1) / BS;
    int gN = (N + BS - 1) / BS;

    zero_kernel<<<gN, BS, 0, stream>>>((float*)cnt, N);
    zero_kernel<<<1, 32, 0, stream>>>(bn_acc, 32);

    // CSR build: one atomic per edge total
    rank_kernel<<<gE, BS, 0, stream>>>(ei, cnt, rank, E);
    int nb = (N + 1023) / 1024;
    scan1<<<nb, 1024, 0, stream>>>(cnt, row_ptr, blockSums, N);
    scan2<<<1, 64, 0, stream>>>(blockSums, nb);
    scan3<<<nb, 1024, 0, stream>>>(row_ptr, blockSums, N, E);
    place2<<<gE, BS, 0, stream>>>(ei, ew, rank, row_ptr, csr, E);
    wdeg_dis<<<gN, BS, 0, stream>>>(csr, row_ptr, dis, N);
    normk<<<gN, BS, 0, stream>>>(csr, row_ptr, dis, N);

    // ---- conv1 (K=3, H=16, T=4, relu), bf16 features ----
    aggx<<<gN, BS, 0, stream>>>(x, row_ptr, csr, y1, N);
    int g64 = (N * 64 + BS - 1) / BS;
    init48<<<g64, BS, 0, stream>>>(x, y1, w1_init, w1_root, w1_b, bufP, N);
    int gAgg = (N + 3) / 4;  // wave per node
    agg48u<<<gAgg, BS, 0, stream>>>(bufP, w1_w, x, w1_root, w1_b, row_ptr, csr, bufQ, N);
    agg48u<<<gAgg, BS, 0, stream>>>(bufQ, w1_w, x, w1_root, w1_b, row_ptr, csr, bufP, N);
    agg48u<<<gAgg, BS, 0, stream>>>(bufP, w1_w, x, w1_root, w1_b, row_ptr, csr, bufQ, N);
    // conv1 output in bufQ

    // ---- batchnorm (fused coefs) ----
    bn_stats<<<512, 256, 0, stream>>>(bufQ, bn_acc, N);
    bn_final<<<1, 16, 0, stream>>>(bn_acc, bn1_g, bn1_b, bn_coef, N);

    // ---- conv2 collapsed to scalar Horner chain ----
    cvec_prep<<<1, 64, 0, stream>>>(w2_w, w2_init, w2_root, w2_b, cvec);
    conv2_init<<<gN, BS, 0, stream>>>(bufQ, bn_coef, cvec, zA, Rbuf, N);
    horner<0><<<gN, BS, 0, stream>>>(zA, (const float*)Rbuf, 0, row_ptr, csr, zB, lin_w, lin_b, N);
    horner<0><<<gN, BS, 0, stream>>>(zB, (const float*)Rbuf, 1, row_ptr, csr, zA, lin_w, lin_b, N);
    horner<0><<<gN, BS, 0, stream>>>(zA, (const float*)Rbuf, 2, row_ptr, csr, zB, lin_w, lin_b, N);
    horner<1><<<gN, BS, 0, stream>>>(zB, (const float*)Rbuf, 3, row_ptr, csr, out, lin_w, lin_b, N);
}